// Round 4
// baseline (525.321 us; speedup 1.0000x reference)
//
#include <hip/hip_runtime.h>
#include <math.h>

#define BDIM 64
#define SDIM 2048
#define DDIM 256
#define CHUNKS 32
#define RPC (SDIM / CHUNKS)  // 64 rows per chunk

// ws layout: [0, 256B): per-b arrival counters (int, memset to 0 each launch)
//            [256B, ...): per-(b,chunk) partials (max[256] | sum[256]) floats

// Fused kernel: each block (b, c) computes the masked max/sum partial for its
// 64-row window; the LAST block to finish for batch row b (device-scope atomic
// counter) combines all CHUNKS partials, computes L = sum(mask[b,:]), and
// writes out[b] = [max | sum/L]. Finalize overlaps other blocks' tails and
// saves a kernel launch + stream dependency.
__global__ __launch_bounds__(256) void fe_fused(const float* __restrict__ feats,
                                                const float* __restrict__ mask,
                                                int* __restrict__ counters,
                                                float* __restrict__ partials,
                                                float* __restrict__ out) {
    const int b    = blockIdx.x;
    const int c    = blockIdx.y;
    const int tid  = threadIdx.x;
    const int wave = tid >> 6;
    const int lane = tid & 63;
    const int d4   = lane << 2;   // lane owns float4 at column 4*lane

    const int s0 = c * RPC;

    // Prefix-mask: active rows in this window = sum(mask[b, s0:s0+64])
    __shared__ float s_active;
    if (wave == 0) {
        float m = mask[(size_t)b * SDIM + s0 + lane];
#pragma unroll
        for (int off = 32; off > 0; off >>= 1) m += __shfl_down(m, off, 64);
        if (lane == 0) s_active = m;
    }
    __syncthreads();
    const int active = (int)s_active;

    // contiguous per-wave row range
    const int per = (active + 3) >> 2;
    int sb = wave * per; if (sb > active) sb = active;
    int se = sb + per;   if (se > active) se = active;

    const float* __restrict__ fb = feats + ((size_t)b * SDIM + s0) * DDIM + d4;

    float4 mx = make_float4(-INFINITY, -INFINITY, -INFINITY, -INFINITY);
    float4 sm = make_float4(0.f, 0.f, 0.f, 0.f);

    int s = sb;
    for (; s + 4 <= se; s += 4) {
        const float4 v0 = *(const float4*)(fb + (size_t)(s + 0) * DDIM);
        const float4 v1 = *(const float4*)(fb + (size_t)(s + 1) * DDIM);
        const float4 v2 = *(const float4*)(fb + (size_t)(s + 2) * DDIM);
        const float4 v3 = *(const float4*)(fb + (size_t)(s + 3) * DDIM);
        mx.x = fmaxf(fmaxf(fmaxf(mx.x, v0.x), fmaxf(v1.x, v2.x)), v3.x);
        mx.y = fmaxf(fmaxf(fmaxf(mx.y, v0.y), fmaxf(v1.y, v2.y)), v3.y);
        mx.z = fmaxf(fmaxf(fmaxf(mx.z, v0.z), fmaxf(v1.z, v2.z)), v3.z);
        mx.w = fmaxf(fmaxf(fmaxf(mx.w, v0.w), fmaxf(v1.w, v2.w)), v3.w);
        sm.x += v0.x + v1.x + v2.x + v3.x;
        sm.y += v0.y + v1.y + v2.y + v3.y;
        sm.z += v0.z + v1.z + v2.z + v3.z;
        sm.w += v0.w + v1.w + v2.w + v3.w;
    }
    for (; s < se; ++s) {
        const float4 v = *(const float4*)(fb + (size_t)s * DDIM);
        mx.x = fmaxf(mx.x, v.x); mx.y = fmaxf(mx.y, v.y);
        mx.z = fmaxf(mx.z, v.z); mx.w = fmaxf(mx.w, v.w);
        sm.x += v.x; sm.y += v.y; sm.z += v.z; sm.w += v.w;
    }

    // cross-wave reduce in LDS; wave 0 writes this block's partial
    __shared__ float4 s_mx[256];
    __shared__ float4 s_sm[256];
    s_mx[tid] = mx;
    s_sm[tid] = sm;
    __syncthreads();

    if (wave == 0) {
#pragma unroll
        for (int w = 1; w < 4; ++w) {
            const float4 a = s_mx[w * 64 + lane];
            const float4 t = s_sm[w * 64 + lane];
            mx.x = fmaxf(mx.x, a.x); mx.y = fmaxf(mx.y, a.y);
            mx.z = fmaxf(mx.z, a.z); mx.w = fmaxf(mx.w, a.w);
            sm.x += t.x; sm.y += t.y; sm.z += t.z; sm.w += t.w;
        }
        float* __restrict__ wout = partials + ((size_t)b * CHUNKS + c) * (2 * DDIM);
        *(float4*)(wout + d4)        = mx;
        *(float4*)(wout + DDIM + d4) = sm;
    }

    // release our partial device-wide, then arrive at the per-b counter
    __threadfence();
    __syncthreads();
    __shared__ int s_last;
    if (tid == 0) s_last = (atomicAdd(&counters[b], 1) == CHUNKS - 1);
    __syncthreads();
    if (!s_last) return;
    __threadfence();  // acquire: other blocks' partials now visible

    // ---- finalize batch row b (only the last-arriving block gets here) ----
    // L = sum(mask[b, :])  (8 KB, L2-hot)
    const float4* __restrict__ mb4 = (const float4*)(mask + (size_t)b * SDIM);
    const float4 a4 = mb4[tid];
    const float4 b4 = mb4[tid + 256];
    float part = a4.x + a4.y + a4.z + a4.w + b4.x + b4.y + b4.z + b4.w;
#pragma unroll
    for (int off = 32; off > 0; off >>= 1) part += __shfl_down(part, off, 64);
    __shared__ float wsum[4];
    if (lane == 0) wsum[wave] = part;
    __syncthreads();
    const float L = wsum[0] + wsum[1] + wsum[2] + wsum[3];

    // combine partials: thread tid owns column d = tid
    float cmx = -INFINITY;
    float csm = 0.f;
    const float* __restrict__ base = partials + (size_t)b * CHUNKS * (2 * DDIM);
#pragma unroll 8
    for (int c2 = 0; c2 < CHUNKS; ++c2) {
        cmx = fmaxf(cmx, base[(size_t)c2 * (2 * DDIM) + tid]);
        csm += base[(size_t)c2 * (2 * DDIM) + DDIM + tid];
    }

    float* __restrict__ ob = out + (size_t)b * (2 * DDIM);
    ob[tid]        = cmx;
    ob[DDIM + tid] = csm / L;
}

extern "C" void kernel_launch(void* const* d_in, const int* in_sizes, int n_in,
                              void* d_out, int out_size, void* d_ws, size_t ws_size,
                              hipStream_t stream) {
    const float* feats = (const float*)d_in[0];
    const float* mask  = (const float*)d_in[1];
    float* out         = (float*)d_out;
    int* counters      = (int*)d_ws;                    // 64 ints = 256 B
    float* partials    = (float*)d_ws + BDIM;           // 16B-aligned

    hipMemsetAsync(counters, 0, BDIM * sizeof(int), stream);
    dim3 grid(BDIM, CHUNKS);
    fe_fused<<<grid, 256, 0, stream>>>(feats, mask, counters, partials, out);
}

// Round 5
// 181.119 us; speedup vs baseline: 2.9004x; 2.9004x over previous
//
#include <hip/hip_runtime.h>
#include <math.h>

#define BDIM 64
#define SDIM 2048
#define DDIM 256
#define CHUNKS 32
#define RPC (SDIM / CHUNKS)  // 64 rows per chunk

// ws layout: B*CHUNKS*2*D floats of per-(b,chunk) partials (max[256] | sum[256])

// Kernel 1: partial max/sum over rows [s0, s0 + active) of a 64-row window.
// Flat grid + swizzle: linear block l -> b = l>>5, c = (l&31) ^ (l>>5 & 31).
// Without the swizzle, the fully-co-resident grid pins each CU to a single
// batch row (8 chunks of one b) -> CUs with long rows do 2x the mean work.
// The XOR mixes rows and chunk positions per CU -> balanced makespan.
__global__ __launch_bounds__(256) void fe_partial(const float* __restrict__ feats,
                                                  const float* __restrict__ mask,
                                                  float* __restrict__ partials) {
    const int l    = blockIdx.x;
    const int b    = l >> 5;
    const int c    = (l & 31) ^ (b & 31);
    const int tid  = threadIdx.x;
    const int wave = tid >> 6;
    const int lane = tid & 63;
    const int d4   = lane << 2;   // lane owns float4 at column 4*lane

    const int s0 = c * RPC;

    // Prefix-mask: active rows in this window = sum(mask[b, s0:s0+64])
    __shared__ float s_active;
    if (wave == 0) {
        float m = mask[(size_t)b * SDIM + s0 + lane];  // 64 floats, coalesced
#pragma unroll
        for (int off = 32; off > 0; off >>= 1) m += __shfl_down(m, off, 64);
        if (lane == 0) s_active = m;
    }
    __syncthreads();
    const int active = (int)s_active;

    // contiguous per-wave row range
    const int per = (active + 3) >> 2;
    int sb = wave * per; if (sb > active) sb = active;
    int se = sb + per;   if (se > active) se = active;

    const float* __restrict__ fb = feats + ((size_t)b * SDIM + s0) * DDIM + d4;

    float4 mx = make_float4(-INFINITY, -INFINITY, -INFINITY, -INFINITY);
    float4 sm = make_float4(0.f, 0.f, 0.f, 0.f);

    int s = sb;
    for (; s + 4 <= se; s += 4) {
        const float4 v0 = *(const float4*)(fb + (size_t)(s + 0) * DDIM);
        const float4 v1 = *(const float4*)(fb + (size_t)(s + 1) * DDIM);
        const float4 v2 = *(const float4*)(fb + (size_t)(s + 2) * DDIM);
        const float4 v3 = *(const float4*)(fb + (size_t)(s + 3) * DDIM);
        mx.x = fmaxf(fmaxf(fmaxf(mx.x, v0.x), fmaxf(v1.x, v2.x)), v3.x);
        mx.y = fmaxf(fmaxf(fmaxf(mx.y, v0.y), fmaxf(v1.y, v2.y)), v3.y);
        mx.z = fmaxf(fmaxf(fmaxf(mx.z, v0.z), fmaxf(v1.z, v2.z)), v3.z);
        mx.w = fmaxf(fmaxf(fmaxf(mx.w, v0.w), fmaxf(v1.w, v2.w)), v3.w);
        sm.x += v0.x + v1.x + v2.x + v3.x;
        sm.y += v0.y + v1.y + v2.y + v3.y;
        sm.z += v0.z + v1.z + v2.z + v3.z;
        sm.w += v0.w + v1.w + v2.w + v3.w;
    }
    for (; s < se; ++s) {
        const float4 v = *(const float4*)(fb + (size_t)s * DDIM);
        mx.x = fmaxf(mx.x, v.x); mx.y = fmaxf(mx.y, v.y);
        mx.z = fmaxf(mx.z, v.z); mx.w = fmaxf(mx.w, v.w);
        sm.x += v.x; sm.y += v.y; sm.z += v.z; sm.w += v.w;
    }

    __shared__ float4 s_mx[256];
    __shared__ float4 s_sm[256];
    s_mx[tid] = mx;
    s_sm[tid] = sm;
    __syncthreads();

    if (wave == 0) {
#pragma unroll
        for (int w = 1; w < 4; ++w) {
            const float4 a = s_mx[w * 64 + lane];
            const float4 t = s_sm[w * 64 + lane];
            mx.x = fmaxf(mx.x, a.x); mx.y = fmaxf(mx.y, a.y);
            mx.z = fmaxf(mx.z, a.z); mx.w = fmaxf(mx.w, a.w);
            sm.x += t.x; sm.y += t.y; sm.z += t.z; sm.w += t.w;
        }
        float* __restrict__ wout = partials + ((size_t)b * CHUNKS + c) * (2 * DDIM);
        *(float4*)(wout + d4)        = mx;
        *(float4*)(wout + DDIM + d4) = sm;
    }
}

// Kernel 2: reduce CHUNKS partials per (b, d); compute L = sum(mask[b,:]);
// out[b] = [max | sum/L].
__global__ __launch_bounds__(256) void fe_combine(const float* __restrict__ partials,
                                                  const float* __restrict__ mask,
                                                  float* __restrict__ out) {
    const int b    = blockIdx.x;
    const int tid  = threadIdx.x;
    const int wave = tid >> 6;
    const int lane = tid & 63;

    // L = sum over S of mask[b, :]  (8 KB, L2/L3-hot)
    const float4* __restrict__ mb = (const float4*)(mask + (size_t)b * SDIM);
    const float4 a = mb[tid];
    const float4 c4 = mb[tid + 256];
    float part = a.x + a.y + a.z + a.w + c4.x + c4.y + c4.z + c4.w;
#pragma unroll
    for (int off = 32; off > 0; off >>= 1) part += __shfl_down(part, off, 64);
    __shared__ float wsum[4];
    if (lane == 0) wsum[wave] = part;
    __syncthreads();
    const float L = wsum[0] + wsum[1] + wsum[2] + wsum[3];

    // combine partials: thread tid owns column d = tid
    float mx = -INFINITY;
    float sm = 0.f;
    const float* __restrict__ base = partials + (size_t)b * CHUNKS * (2 * DDIM);
#pragma unroll 8
    for (int c = 0; c < CHUNKS; ++c) {
        mx = fmaxf(mx, base[(size_t)c * (2 * DDIM) + tid]);
        sm += base[(size_t)c * (2 * DDIM) + DDIM + tid];
    }

    float* __restrict__ ob = out + (size_t)b * (2 * DDIM);
    ob[tid]        = mx;
    ob[DDIM + tid] = sm / L;
}

extern "C" void kernel_launch(void* const* d_in, const int* in_sizes, int n_in,
                              void* d_out, int out_size, void* d_ws, size_t ws_size,
                              hipStream_t stream) {
    const float* feats = (const float*)d_in[0];
    const float* mask  = (const float*)d_in[1];
    float* out         = (float*)d_out;
    float* partials    = (float*)d_ws;

    fe_partial<<<BDIM * CHUNKS, 256, 0, stream>>>(feats, mask, partials);
    fe_combine<<<BDIM, 256, 0, stream>>>(partials, mask, out);
}